// Round 1
// baseline (1203.010 us; speedup 1.0000x reference)
//
#include <hip/hip_runtime.h>

// Mamba3 SSM layer: B=2, L=2048, D_MODEL=1024, D_INNER=2048, D_STATE=32
#define DM   1024
#define DI   2048
#define DST  32
#define NB   2
#define LSEQ 2048
#define BL   (NB*LSEQ)   // 4096 rows

using bf16   = __bf16;
using bf16x4 = __attribute__((ext_vector_type(4))) __bf16;
using bf16x8 = __attribute__((ext_vector_type(8))) __bf16;
using f32x4  = __attribute__((ext_vector_type(4))) float;

static __device__ __forceinline__ float sigmoidf_(float x) {
  return 1.f / (1.f + __expf(-x));
}

// ---------------- cast kernels ----------------
__global__ __launch_bounds__(256) void cast_bf16_kernel(
    const float* __restrict__ in, bf16* __restrict__ out, int n4) {
  int i = blockIdx.x * 256 + threadIdx.x;
  if (i >= n4) return;
  f32x4 v = ((const f32x4*)in)[i];
  bf16x4 o;
  #pragma unroll
  for (int j = 0; j < 4; ++j) o[j] = (bf16)v[j];
  ((bf16x4*)out)[i] = o;
}

// W_xproj (65,2048) -> bf16 padded to (128,2048), rows 65..127 zero
__global__ __launch_bounds__(256) void padcast_wxp_kernel(
    const float* __restrict__ in, bf16* __restrict__ out) {
  int i = blockIdx.x * 256 + threadIdx.x;   // over 128*2048/4 = 65536
  int k4 = i & 511;
  int n  = i >> 9;
  f32x4 v = {0.f, 0.f, 0.f, 0.f};
  if (n < 65) v = *(const f32x4*)(in + (size_t)n * 2048 + k4 * 4);
  bf16x4 o;
  #pragma unroll
  for (int j = 0; j < 4; ++j) o[j] = (bf16)v[j];
  ((bf16x4*)out)[i] = o;
}

// ---------------- bf16 MFMA GEMM: C[M][N] = A[M][K] * B[N][K]^T ----------------
// 128x128 tile, BK=32, 4 waves (2x2), each wave 64x64 via 4x4 16x16 fragments.
__global__ __launch_bounds__(256) void gemm_bt(
    const bf16* __restrict__ A, const bf16* __restrict__ B,
    float* __restrict__ C, int M, int N, int K) {
  __shared__ bf16 As[128][40];   // pad 32->40 shorts: 80B row stride (16B aligned)
  __shared__ bf16 Bs[128][40];

  int tid  = threadIdx.x;
  int bm   = blockIdx.y, bn = blockIdx.x;
  int row0 = bm * 128, col0 = bn * 128;
  int w    = tid >> 6, lane = tid & 63;
  int wr   = w >> 1, wc = w & 1;
  int lr   = lane & 15, lk = lane >> 4;

  f32x4 acc[4][4];
  #pragma unroll
  for (int i = 0; i < 4; ++i)
    #pragma unroll
    for (int j = 0; j < 4; ++j) acc[i][j] = f32x4{0.f, 0.f, 0.f, 0.f};

  int srow = tid >> 1;
  int scol = (tid & 1) * 16;
  const bf16* Ag = A + (size_t)(row0 + srow) * K + scol;
  const bf16* Bg = B + (size_t)(col0 + srow) * K + scol;

  for (int k0 = 0; k0 < K; k0 += 32) {
    *(bf16x8*)&As[srow][scol]     = *(const bf16x8*)(Ag + k0);
    *(bf16x8*)&As[srow][scol + 8] = *(const bf16x8*)(Ag + k0 + 8);
    *(bf16x8*)&Bs[srow][scol]     = *(const bf16x8*)(Bg + k0);
    *(bf16x8*)&Bs[srow][scol + 8] = *(const bf16x8*)(Bg + k0 + 8);
    __syncthreads();

    bf16x8 af[4], bff[4];
    #pragma unroll
    for (int mi = 0; mi < 4; ++mi)
      af[mi] = *(const bf16x8*)&As[wr * 64 + mi * 16 + lr][lk * 8];
    #pragma unroll
    for (int ni = 0; ni < 4; ++ni)
      bff[ni] = *(const bf16x8*)&Bs[wc * 64 + ni * 16 + lr][lk * 8];

    #pragma unroll
    for (int mi = 0; mi < 4; ++mi)
      #pragma unroll
      for (int ni = 0; ni < 4; ++ni)
        acc[mi][ni] = __builtin_amdgcn_mfma_f32_16x16x32_bf16(
            af[mi], bff[ni], acc[mi][ni], 0, 0, 0);
    __syncthreads();
  }

  // C/D layout: col = lane&15, row = (lane>>4)*4 + reg  [m89-verified]
  #pragma unroll
  for (int mi = 0; mi < 4; ++mi)
    #pragma unroll
    for (int ni = 0; ni < 4; ++ni) {
      int r0 = row0 + wr * 64 + mi * 16 + lk * 4;
      int c  = col0 + wc * 64 + ni * 16 + lr;
      #pragma unroll
      for (int r = 0; r < 4; ++r)
        C[(size_t)(r0 + r) * N + c] = acc[mi][ni][r];
    }
}

// ---------------- depthwise conv3 + SiLU -> bf16 ----------------
// x_in = xz[:, :, 0:2048]; out x_conv bf16 (BL, DI)
__global__ __launch_bounds__(256) void conv_silu_kernel(
    const float* __restrict__ xz, bf16* __restrict__ xconv,
    const float* __restrict__ conv_w, const float* __restrict__ conv_b) {
  int i = blockIdx.x * 256 + threadIdx.x;  // over BL * DI/4 = 2,097,152
  int d4 = i & 511;
  int d  = d4 * 4;
  int bl = i >> 9;
  int l  = bl & (LSEQ - 1);

  const float* base = xz + (size_t)bl * (2 * DI) + d;
  f32x4 zero = {0.f, 0.f, 0.f, 0.f};
  f32x4 xm = (l > 0)        ? *(const f32x4*)(base - 2 * DI) : zero;
  f32x4 xc = *(const f32x4*)(base);
  f32x4 xp = (l < LSEQ - 1) ? *(const f32x4*)(base + 2 * DI) : zero;

  bf16x4 o;
  #pragma unroll
  for (int j = 0; j < 4; ++j) {
    float w0 = conv_w[(d + j) * 3 + 0];
    float w1 = conv_w[(d + j) * 3 + 1];
    float w2 = conv_w[(d + j) * 3 + 2];
    float v = fmaf(w0, xm[j], fmaf(w1, xc[j], fmaf(w2, xp[j], conv_b[d + j])));
    v = v * sigmoidf_(v);  // SiLU
    o[j] = (bf16)v;
  }
  *(bf16x4*)(xconv + (size_t)bl * DI + d) = o;
}

// ---------------- sequential SSM scan ----------------
// wave = 2 channels x 32 states; lane = half*32 + n; h is one register.
__global__ __launch_bounds__(256) void scan_kernel(
    const float* __restrict__ proj,    // (BL, 128) padded: [0]=dt_raw, [1..32]=B, [33..64]=C
    const bf16*  __restrict__ xconv,   // (BL, DI)
    const float* __restrict__ A_log,   // (DI, 32)
    const float* __restrict__ D_skip,  // (DI,)
    const float* __restrict__ W_dt,    // (DI,1)
    const float* __restrict__ b_dt,    // (DI,)
    const float* __restrict__ alpha,   // scalar
    bf16* __restrict__ ys)             // (BL, DI) bf16
{
  int wid  = threadIdx.x >> 6;
  int lane = threadIdx.x & 63;
  int half = lane >> 5;
  int n    = lane & 31;
  int pair = blockIdx.x * 4 + wid;          // 0..2047 = NB * DI/2
  int b    = pair >> 10;
  int d    = ((pair & 1023) << 1) | half;

  float A_real = -__expf(A_log[d * DST + n]);
  float Wdt = W_dt[d];
  float bdt = b_dt[d];
  float Dsk = D_skip[d];
  float aG  = sigmoidf_(alpha[0]);
  float omA = 1.f - aG;

  const float* pb = proj + (size_t)b * LSEQ * 128;
  const bf16*  uc = xconv + (size_t)b * LSEQ * DI + d;
  bf16*        yc = ys    + (size_t)b * LSEQ * DI + d;

  float h = 0.f;
  #pragma unroll 2
  for (int t = 0; t < LSEQ; ++t) {
    const float* p = pb + (size_t)t * 128;
    float dtraw = p[0];
    float Bv    = p[1 + n];
    float Cv    = p[33 + n];
    float u     = (float)uc[(size_t)t * DI];

    float s  = fmaf(dtraw, Wdt, bdt);
    float dt = (s > 15.f) ? s : __logf(1.f + __expf(s));  // softplus
    float dtA = A_real * dt;
    float rec = __builtin_amdgcn_rcpf(fmaf(-0.5f, dtA, 1.000001f));
    float Ad  = fmaf(aG, __expf(dtA), omA * rec);
    h = fmaf(Ad, h, dt * u * Bv);

    float part = Cv * h;
    part += __shfl_xor(part, 1);
    part += __shfl_xor(part, 2);
    part += __shfl_xor(part, 4);
    part += __shfl_xor(part, 8);
    part += __shfl_xor(part, 16);
    if (n == 0) yc[(size_t)t * DI] = (bf16)(part + Dsk * u);
  }
}

// ---------------- gate: y = ys * silu(z) -> bf16 ----------------
__global__ __launch_bounds__(256) void gate_kernel(
    const bf16* __restrict__ ys, const float* __restrict__ xz,
    bf16* __restrict__ yb) {
  int i  = blockIdx.x * 256 + threadIdx.x;  // over BL*DI/4
  int bl = i >> 9;
  int d4 = (i & 511) * 4;
  f32x4 z = *(const f32x4*)(xz + (size_t)bl * (2 * DI) + DI + d4);
  bf16x4 y = ((const bf16x4*)ys)[i];
  bf16x4 o;
  #pragma unroll
  for (int j = 0; j < 4; ++j) {
    float f = (float)y[j] * (z[j] * sigmoidf_(z[j]));
    o[j] = (bf16)f;
  }
  ((bf16x4*)yb)[i] = o;
}

// ---------------- launch ----------------
extern "C" void kernel_launch(void* const* d_in, const int* in_sizes, int n_in,
                              void* d_out, int out_size, void* d_ws, size_t ws_size,
                              hipStream_t stream) {
  const float* x      = (const float*)d_in[0];
  const float* W_in   = (const float*)d_in[1];
  const float* conv_w = (const float*)d_in[2];
  const float* conv_b = (const float*)d_in[3];
  const float* A_log  = (const float*)d_in[4];
  const float* D_skip = (const float*)d_in[5];
  const float* W_xprj = (const float*)d_in[6];
  const float* W_dt   = (const float*)d_in[7];
  const float* b_dt   = (const float*)d_in[8];
  const float* alpha  = (const float*)d_in[9];
  const float* W_out  = (const float*)d_in[10];

  char* ws = (char*)d_ws;
  float* xz    = (float*)(ws + 0);            // (4096,4096) f32: 67,108,864 B
  bf16*  xconv = (bf16*) (ws + 67108864);     // (4096,2048) bf16: 16,777,216 B
  float* proj  = (float*)(ws + 83886080);     // (4096,128)  f32:  2,097,152 B
  bf16*  ysb   = (bf16*) (ws + 85983232);     // (4096,2048) bf16: 16,777,216 B
  bf16*  yb    = (bf16*) (ws + 102760448);    // (4096,2048) bf16: 16,777,216 B
  bf16*  xb    = (bf16*) (ws + 119537664);    // (4096,1024) bf16:  8,388,608 B
  bf16*  winb  = (bf16*) (ws + 127926272);    // (4096,1024) bf16:  8,388,608 B
  bf16*  woutb = (bf16*) (ws + 136314880);    // (1024,2048) bf16:  4,194,304 B
  bf16*  wxpb  = (bf16*) (ws + 140509184);    // (128,2048)  bf16:    524,288 B
  // total: 141,033,472 B

  float* out = (float*)d_out;  // (4096, 1024) f32

  // casts
  cast_bf16_kernel<<<4096, 256, 0, stream>>>(x, xb, BL * DM / 4);
  cast_bf16_kernel<<<4096, 256, 0, stream>>>(W_in, winb, 2 * DI * DM / 4);
  cast_bf16_kernel<<<2048, 256, 0, stream>>>(W_out, woutb, DM * DI / 4);
  padcast_wxp_kernel<<<256, 256, 0, stream>>>(W_xprj, wxpb);

  // xz = x @ W_in.T   (M=4096, N=4096, K=1024)
  gemm_bt<<<dim3(32, 32), 256, 0, stream>>>(xb, winb, xz, BL, 2 * DI, DM);

  // x_conv = silu(conv1d(x_in))
  conv_silu_kernel<<<8192, 256, 0, stream>>>(xz, xconv, conv_w, conv_b);

  // proj = x_conv @ W_xproj.T  (N padded to 128)
  gemm_bt<<<dim3(1, 32), 256, 0, stream>>>(xconv, wxpb, proj, BL, 128, DI);

  // sequential scan
  scan_kernel<<<512, 256, 0, stream>>>(proj, xconv, A_log, D_skip, W_dt, b_dt,
                                       alpha, ysb);

  // y = ys * silu(z)
  gate_kernel<<<8192, 256, 0, stream>>>(ysb, xz, yb);

  // out = y @ W_out.T  (M=4096, N=1024, K=2048)
  gemm_bt<<<dim3(8, 32), 256, 0, stream>>>(yb, woutb, out, BL, DM, DI);
}

// Round 2
// 747.552 us; speedup vs baseline: 1.6093x; 1.6093x over previous
//
#include <hip/hip_runtime.h>

// Mamba3 SSM layer: B=2, L=2048, D_MODEL=1024, D_INNER=2048, D_STATE=32
#define DM   1024
#define DI   2048
#define DST  32
#define NB   2
#define LSEQ 2048
#define BL   (NB*LSEQ)   // 4096 rows
#define LC   128         // scan chunk length
#define NC   16          // number of chunks (LC*NC == LSEQ)

using bf16   = __bf16;
using bf16x4 = __attribute__((ext_vector_type(4))) __bf16;
using bf16x8 = __attribute__((ext_vector_type(8))) __bf16;
using f32x4  = __attribute__((ext_vector_type(4))) float;

static __device__ __forceinline__ float sigmoidf_(float x) {
  return 1.f / (1.f + __expf(-x));
}

// ---------------- cast kernels ----------------
__global__ __launch_bounds__(256) void cast_bf16_kernel(
    const float* __restrict__ in, bf16* __restrict__ out, int n4) {
  int i = blockIdx.x * 256 + threadIdx.x;
  if (i >= n4) return;
  f32x4 v = ((const f32x4*)in)[i];
  bf16x4 o;
  #pragma unroll
  for (int j = 0; j < 4; ++j) o[j] = (bf16)v[j];
  ((bf16x4*)out)[i] = o;
}

// W_xproj (65,2048) -> bf16 padded to (128,2048), rows 65..127 zero
__global__ __launch_bounds__(256) void padcast_wxp_kernel(
    const float* __restrict__ in, bf16* __restrict__ out) {
  int i = blockIdx.x * 256 + threadIdx.x;   // over 128*2048/4 = 65536
  int k4 = i & 511;
  int n  = i >> 9;
  f32x4 v = {0.f, 0.f, 0.f, 0.f};
  if (n < 65) v = *(const f32x4*)(in + (size_t)n * 2048 + k4 * 4);
  bf16x4 o;
  #pragma unroll
  for (int j = 0; j < 4; ++j) o[j] = (bf16)v[j];
  ((bf16x4*)out)[i] = o;
}

// ---------------- bf16 MFMA GEMM: C[M][N] = A[M][K] * B[N][K]^T ----------------
__global__ __launch_bounds__(256) void gemm_bt(
    const bf16* __restrict__ A, const bf16* __restrict__ B,
    float* __restrict__ C, int M, int N, int K) {
  __shared__ bf16 As[128][40];
  __shared__ bf16 Bs[128][40];

  int tid  = threadIdx.x;
  int bm   = blockIdx.y, bn = blockIdx.x;
  int row0 = bm * 128, col0 = bn * 128;
  int w    = tid >> 6, lane = tid & 63;
  int wr   = w >> 1, wc = w & 1;
  int lr   = lane & 15, lk = lane >> 4;

  f32x4 acc[4][4];
  #pragma unroll
  for (int i = 0; i < 4; ++i)
    #pragma unroll
    for (int j = 0; j < 4; ++j) acc[i][j] = f32x4{0.f, 0.f, 0.f, 0.f};

  int srow = tid >> 1;
  int scol = (tid & 1) * 16;
  const bf16* Ag = A + (size_t)(row0 + srow) * K + scol;
  const bf16* Bg = B + (size_t)(col0 + srow) * K + scol;

  for (int k0 = 0; k0 < K; k0 += 32) {
    *(bf16x8*)&As[srow][scol]     = *(const bf16x8*)(Ag + k0);
    *(bf16x8*)&As[srow][scol + 8] = *(const bf16x8*)(Ag + k0 + 8);
    *(bf16x8*)&Bs[srow][scol]     = *(const bf16x8*)(Bg + k0);
    *(bf16x8*)&Bs[srow][scol + 8] = *(const bf16x8*)(Bg + k0 + 8);
    __syncthreads();

    bf16x8 af[4], bff[4];
    #pragma unroll
    for (int mi = 0; mi < 4; ++mi)
      af[mi] = *(const bf16x8*)&As[wr * 64 + mi * 16 + lr][lk * 8];
    #pragma unroll
    for (int ni = 0; ni < 4; ++ni)
      bff[ni] = *(const bf16x8*)&Bs[wc * 64 + ni * 16 + lr][lk * 8];

    #pragma unroll
    for (int mi = 0; mi < 4; ++mi)
      #pragma unroll
      for (int ni = 0; ni < 4; ++ni)
        acc[mi][ni] = __builtin_amdgcn_mfma_f32_16x16x32_bf16(
            af[mi], bff[ni], acc[mi][ni], 0, 0, 0);
    __syncthreads();
  }

  #pragma unroll
  for (int mi = 0; mi < 4; ++mi)
    #pragma unroll
    for (int ni = 0; ni < 4; ++ni) {
      int r0 = row0 + wr * 64 + mi * 16 + lk * 4;
      int c  = col0 + wc * 64 + ni * 16 + lr;
      #pragma unroll
      for (int r = 0; r < 4; ++r)
        C[(size_t)(r0 + r) * N + c] = acc[mi][ni][r];
    }
}

// ---------------- depthwise conv3 + SiLU -> bf16 ----------------
__global__ __launch_bounds__(256) void conv_silu_kernel(
    const float* __restrict__ xz, bf16* __restrict__ xconv,
    const float* __restrict__ conv_w, const float* __restrict__ conv_b) {
  int i = blockIdx.x * 256 + threadIdx.x;  // over BL * DI/4
  int d4 = i & 511;
  int d  = d4 * 4;
  int bl = i >> 9;
  int l  = bl & (LSEQ - 1);

  const float* base = xz + (size_t)bl * (2 * DI) + d;
  f32x4 zero = {0.f, 0.f, 0.f, 0.f};
  f32x4 xm = (l > 0)        ? *(const f32x4*)(base - 2 * DI) : zero;
  f32x4 xc = *(const f32x4*)(base);
  f32x4 xp = (l < LSEQ - 1) ? *(const f32x4*)(base + 2 * DI) : zero;

  bf16x4 o;
  #pragma unroll
  for (int j = 0; j < 4; ++j) {
    float w0 = conv_w[(d + j) * 3 + 0];
    float w1 = conv_w[(d + j) * 3 + 1];
    float w2 = conv_w[(d + j) * 3 + 2];
    float v = fmaf(w0, xm[j], fmaf(w1, xc[j], fmaf(w2, xp[j], conv_b[d + j])));
    v = v * sigmoidf_(v);
    o[j] = (bf16)v;
  }
  *(bf16x4*)(xconv + (size_t)bl * DI + d) = o;
}

// ---------------- chunked SSM scan ----------------
// wave = 2 channels x 32 states; lane = half*32 + n.
// Phase 1: per chunk, P = prod(Ad), h_loc = scan from 0.
// Phase 2: prefix-combine across chunks, store chunk start states.
// Phase 3: re-run chunk from true start state, emit y.

static __device__ __forceinline__ void ssm_step(
    const float* __restrict__ p, float u, int n,
    float Wdt, float bdt, float A_real, float aG, float omA,
    float& Ad, float& bterm) {
  float s  = fmaf(p[0], Wdt, bdt);
  float dt = (s > 15.f) ? s : __logf(1.f + __expf(s));  // softplus
  float dtA = A_real * dt;
  float r  = __builtin_amdgcn_rcpf(fmaf(-0.5f, dtA, 1.000001f));
  Ad    = fmaf(aG, __expf(dtA), omA * r);
  bterm = dt * u * p[1 + n];
}

__global__ __launch_bounds__(256) void scan_phase1(
    const float* __restrict__ proj, const bf16* __restrict__ xconv,
    const float* __restrict__ A_log, const float* __restrict__ W_dt,
    const float* __restrict__ b_dt, const float* __restrict__ alpha,
    float* __restrict__ Pbuf, float* __restrict__ Hbuf) {
  int wid = threadIdx.x >> 6, lane = threadIdx.x & 63;
  int half = lane >> 5, n = lane & 31;
  int pair = blockIdx.x * 4 + wid;   // 0..2047
  int c = blockIdx.y;                // 0..NC-1
  int b = pair >> 10;
  int d = ((pair & 1023) << 1) | half;

  float A_real = -__expf(A_log[d * DST + n]);
  float Wdt = W_dt[d], bdt = b_dt[d];
  float aG  = sigmoidf_(alpha[0]), omA = 1.f - aG;

  const float* pb = proj  + ((size_t)b * LSEQ + c * LC) * 128;
  const bf16*  uc = xconv + ((size_t)b * LSEQ + c * LC) * DI + d;

  float h = 0.f, P = 1.f;
  #pragma unroll 4
  for (int t = 0; t < LC; ++t) {
    const float* p = pb + (size_t)t * 128;
    float u = (float)uc[(size_t)t * DI];
    float Ad, bterm;
    ssm_step(p, u, n, Wdt, bdt, A_real, aG, omA, Ad, bterm);
    h = fmaf(Ad, h, bterm);
    P *= Ad;
  }
  size_t idx = ((size_t)c * 2048 + pair) * 64 + lane;
  Pbuf[idx] = P;
  Hbuf[idx] = h;
}

__global__ __launch_bounds__(256) void scan_phase2(
    const float* __restrict__ Pbuf, float* __restrict__ Hbuf) {
  int wid = threadIdx.x >> 6, lane = threadIdx.x & 63;
  int pair = blockIdx.x * 4 + wid;
  float P[NC], hl[NC];
  #pragma unroll
  for (int c = 0; c < NC; ++c) {
    size_t idx = ((size_t)c * 2048 + pair) * 64 + lane;
    P[c]  = Pbuf[idx];
    hl[c] = Hbuf[idx];
  }
  float H = 0.f;
  #pragma unroll
  for (int c = 0; c < NC; ++c) {
    size_t idx = ((size_t)c * 2048 + pair) * 64 + lane;
    Hbuf[idx] = H;              // start state for chunk c
    H = fmaf(P[c], H, hl[c]);   // end state of chunk c
  }
}

__global__ __launch_bounds__(256) void scan_phase3(
    const float* __restrict__ proj, const bf16* __restrict__ xconv,
    const float* __restrict__ A_log, const float* __restrict__ D_skip,
    const float* __restrict__ W_dt, const float* __restrict__ b_dt,
    const float* __restrict__ alpha, const float* __restrict__ Hbuf,
    bf16* __restrict__ ys) {
  int wid = threadIdx.x >> 6, lane = threadIdx.x & 63;
  int half = lane >> 5, n = lane & 31;
  int pair = blockIdx.x * 4 + wid;
  int c = blockIdx.y;
  int b = pair >> 10;
  int d = ((pair & 1023) << 1) | half;

  float A_real = -__expf(A_log[d * DST + n]);
  float Wdt = W_dt[d], bdt = b_dt[d];
  float Dsk = D_skip[d];
  float aG  = sigmoidf_(alpha[0]), omA = 1.f - aG;

  const float* pb = proj  + ((size_t)b * LSEQ + c * LC) * 128;
  const bf16*  uc = xconv + ((size_t)b * LSEQ + c * LC) * DI + d;
  bf16*        yc = ys    + ((size_t)b * LSEQ + c * LC) * DI + d;

  float h = Hbuf[((size_t)c * 2048 + pair) * 64 + lane];

  #pragma unroll 2
  for (int t = 0; t < LC; ++t) {
    const float* p = pb + (size_t)t * 128;
    float u = (float)uc[(size_t)t * DI];
    float Ad, bterm;
    ssm_step(p, u, n, Wdt, bdt, A_real, aG, omA, Ad, bterm);
    h = fmaf(Ad, h, bterm);

    float part = p[33 + n] * h;
    part += __shfl_xor(part, 1);
    part += __shfl_xor(part, 2);
    part += __shfl_xor(part, 4);
    part += __shfl_xor(part, 8);
    part += __shfl_xor(part, 16);
    if (n == 0) yc[(size_t)t * DI] = (bf16)(part + Dsk * u);
  }
}

// ---------------- gate: y = ys * silu(z) -> bf16 ----------------
__global__ __launch_bounds__(256) void gate_kernel(
    const bf16* __restrict__ ys, const float* __restrict__ xz,
    bf16* __restrict__ yb) {
  int i  = blockIdx.x * 256 + threadIdx.x;  // over BL*DI/4
  int bl = i >> 9;
  int d4 = (i & 511) * 4;
  f32x4 z = *(const f32x4*)(xz + (size_t)bl * (2 * DI) + DI + d4);
  bf16x4 y = ((const bf16x4*)ys)[i];
  bf16x4 o;
  #pragma unroll
  for (int j = 0; j < 4; ++j) {
    float f = (float)y[j] * (z[j] * sigmoidf_(z[j]));
    o[j] = (bf16)f;
  }
  ((bf16x4*)yb)[i] = o;
}

// ---------------- launch ----------------
extern "C" void kernel_launch(void* const* d_in, const int* in_sizes, int n_in,
                              void* d_out, int out_size, void* d_ws, size_t ws_size,
                              hipStream_t stream) {
  const float* x      = (const float*)d_in[0];
  const float* W_in   = (const float*)d_in[1];
  const float* conv_w = (const float*)d_in[2];
  const float* conv_b = (const float*)d_in[3];
  const float* A_log  = (const float*)d_in[4];
  const float* D_skip = (const float*)d_in[5];
  const float* W_xprj = (const float*)d_in[6];
  const float* W_dt   = (const float*)d_in[7];
  const float* b_dt   = (const float*)d_in[8];
  const float* alpha  = (const float*)d_in[9];
  const float* W_out  = (const float*)d_in[10];

  char* ws = (char*)d_ws;
  float* xz    = (float*)(ws + 0);            // (4096,4096) f32: 67,108,864 B
  bf16*  xconv = (bf16*) (ws + 67108864);     // (4096,2048) bf16: 16,777,216 B
  float* proj  = (float*)(ws + 83886080);     // (4096,128)  f32:  2,097,152 B
  bf16*  ysb   = (bf16*) (ws + 85983232);     // (4096,2048) bf16: 16,777,216 B
  bf16*  yb    = (bf16*) (ws + 102760448);    // (4096,2048) bf16: 16,777,216 B
  bf16*  xb    = (bf16*) (ws + 119537664);    // (4096,1024) bf16:  8,388,608 B
  bf16*  winb  = (bf16*) (ws + 127926272);    // (4096,1024) bf16:  8,388,608 B
  bf16*  woutb = (bf16*) (ws + 136314880);    // (1024,2048) bf16:  4,194,304 B
  bf16*  wxpb  = (bf16*) (ws + 140509184);    // (128,2048)  bf16:    524,288 B
  // total: 141,033,472 B
  // P/H scan buffers reuse xb/winb (both dead after GEMM1):
  float* Pbuf = (float*)xb;    // 16*2048*64*4 = 8,388,608 B
  float* Hbuf = (float*)winb;  // 8,388,608 B

  float* out = (float*)d_out;  // (4096, 1024) f32

  // casts
  cast_bf16_kernel<<<4096, 256, 0, stream>>>(x, xb, BL * DM / 4);
  cast_bf16_kernel<<<4096, 256, 0, stream>>>(W_in, winb, 2 * DI * DM / 4);
  cast_bf16_kernel<<<2048, 256, 0, stream>>>(W_out, woutb, DM * DI / 4);
  padcast_wxp_kernel<<<256, 256, 0, stream>>>(W_xprj, wxpb);

  // xz = x @ W_in.T   (M=4096, N=4096, K=1024)
  gemm_bt<<<dim3(32, 32), 256, 0, stream>>>(xb, winb, xz, BL, 2 * DI, DM);

  // x_conv = silu(conv1d(x_in))
  conv_silu_kernel<<<8192, 256, 0, stream>>>(xz, xconv, conv_w, conv_b);

  // proj = x_conv @ W_xproj.T  (N padded to 128)
  gemm_bt<<<dim3(1, 32), 256, 0, stream>>>(xconv, wxpb, proj, BL, 128, DI);

  // chunked scan
  scan_phase1<<<dim3(512, NC), 256, 0, stream>>>(proj, xconv, A_log, W_dt,
                                                 b_dt, alpha, Pbuf, Hbuf);
  scan_phase2<<<512, 256, 0, stream>>>(Pbuf, Hbuf);
  scan_phase3<<<dim3(512, NC), 256, 0, stream>>>(proj, xconv, A_log, D_skip,
                                                 W_dt, b_dt, alpha, Hbuf, ysb);

  // y = ys * silu(z)
  gate_kernel<<<8192, 256, 0, stream>>>(ysb, xz, yb);

  // out = y @ W_out.T  (M=4096, N=1024, K=2048)
  gemm_bt<<<dim3(8, 32), 256, 0, stream>>>(yb, woutb, out, BL, DM, DI);
}

// Round 4
// 660.118 us; speedup vs baseline: 1.8224x; 1.1325x over previous
//
#include <hip/hip_runtime.h>

// Mamba3 SSM layer: B=2, L=2048, D_MODEL=1024, D_INNER=2048, D_STATE=32
#define DM   1024
#define DI   2048
#define DST  32
#define NB   2
#define LSEQ 2048
#define BL   (NB*LSEQ)   // 4096 rows
#define LC   128         // scan chunk length
#define NC   16          // number of chunks (LC*NC == LSEQ)

using bf16   = __bf16;
using bf16x4 = __attribute__((ext_vector_type(4))) __bf16;
using bf16x8 = __attribute__((ext_vector_type(8))) __bf16;
using f32x4  = __attribute__((ext_vector_type(4))) float;
using f16x2  = __attribute__((ext_vector_type(2))) _Float16;

static __device__ __forceinline__ float sigmoidf_(float x) {
  return 1.f / (1.f + __expf(-x));
}

static __device__ __forceinline__ f16x2 pack_f16x2(float a, float b) {
  return __builtin_bit_cast(f16x2, __builtin_amdgcn_cvt_pkrtz(a, b));
}

// ---------------- cast kernels ----------------
__global__ __launch_bounds__(256) void cast_bf16_kernel(
    const float* __restrict__ in, bf16* __restrict__ out, int n4) {
  int i = blockIdx.x * 256 + threadIdx.x;
  if (i >= n4) return;
  f32x4 v = ((const f32x4*)in)[i];
  bf16x4 o;
  #pragma unroll
  for (int j = 0; j < 4; ++j) o[j] = (bf16)v[j];
  ((bf16x4*)out)[i] = o;
}

// W_xproj (65,2048) -> bf16 padded to (128,2048), rows 65..127 zero
__global__ __launch_bounds__(256) void padcast_wxp_kernel(
    const float* __restrict__ in, bf16* __restrict__ out) {
  int i = blockIdx.x * 256 + threadIdx.x;   // over 128*2048/4 = 65536
  int k4 = i & 511;
  int n  = i >> 9;
  f32x4 v = {0.f, 0.f, 0.f, 0.f};
  if (n < 65) v = *(const f32x4*)(in + (size_t)n * 2048 + k4 * 4);
  bf16x4 o;
  #pragma unroll
  for (int j = 0; j < 4; ++j) o[j] = (bf16)v[j];
  ((bf16x4*)out)[i] = o;
}

// ---------------- bf16 MFMA GEMM: C[M][N] = A[M][K] * B[N][K]^T ----------------
__global__ __launch_bounds__(256) void gemm_bt(
    const bf16* __restrict__ A, const bf16* __restrict__ B,
    float* __restrict__ C, int M, int N, int K) {
  __shared__ bf16 As[128][40];
  __shared__ bf16 Bs[128][40];

  int tid  = threadIdx.x;
  int bm   = blockIdx.y, bn = blockIdx.x;
  int row0 = bm * 128, col0 = bn * 128;
  int w    = tid >> 6, lane = tid & 63;
  int wr   = w >> 1, wc = w & 1;
  int lr   = lane & 15, lk = lane >> 4;

  f32x4 acc[4][4];
  #pragma unroll
  for (int i = 0; i < 4; ++i)
    #pragma unroll
    for (int j = 0; j < 4; ++j) acc[i][j] = f32x4{0.f, 0.f, 0.f, 0.f};

  int srow = tid >> 1;
  int scol = (tid & 1) * 16;
  const bf16* Ag = A + (size_t)(row0 + srow) * K + scol;
  const bf16* Bg = B + (size_t)(col0 + srow) * K + scol;

  for (int k0 = 0; k0 < K; k0 += 32) {
    *(bf16x8*)&As[srow][scol]     = *(const bf16x8*)(Ag + k0);
    *(bf16x8*)&As[srow][scol + 8] = *(const bf16x8*)(Ag + k0 + 8);
    *(bf16x8*)&Bs[srow][scol]     = *(const bf16x8*)(Bg + k0);
    *(bf16x8*)&Bs[srow][scol + 8] = *(const bf16x8*)(Bg + k0 + 8);
    __syncthreads();

    bf16x8 af[4], bff[4];
    #pragma unroll
    for (int mi = 0; mi < 4; ++mi)
      af[mi] = *(const bf16x8*)&As[wr * 64 + mi * 16 + lr][lk * 8];
    #pragma unroll
    for (int ni = 0; ni < 4; ++ni)
      bff[ni] = *(const bf16x8*)&Bs[wc * 64 + ni * 16 + lr][lk * 8];

    #pragma unroll
    for (int mi = 0; mi < 4; ++mi)
      #pragma unroll
      for (int ni = 0; ni < 4; ++ni)
        acc[mi][ni] = __builtin_amdgcn_mfma_f32_16x16x32_bf16(
            af[mi], bff[ni], acc[mi][ni], 0, 0, 0);
    __syncthreads();
  }

  #pragma unroll
  for (int mi = 0; mi < 4; ++mi)
    #pragma unroll
    for (int ni = 0; ni < 4; ++ni) {
      int r0 = row0 + wr * 64 + mi * 16 + lk * 4;
      int c  = col0 + wc * 64 + ni * 16 + lr;
      #pragma unroll
      for (int r = 0; r < 4; ++r)
        C[(size_t)(r0 + r) * N + c] = acc[mi][ni][r];
    }
}

// ---------------- depthwise conv3 + SiLU -> bf16 ----------------
__global__ __launch_bounds__(256) void conv_silu_kernel(
    const float* __restrict__ xz, bf16* __restrict__ xconv,
    const float* __restrict__ conv_w, const float* __restrict__ conv_b) {
  int i = blockIdx.x * 256 + threadIdx.x;  // over BL * DI/4
  int d4 = i & 511;
  int d  = d4 * 4;
  int bl = i >> 9;
  int l  = bl & (LSEQ - 1);

  const float* base = xz + (size_t)bl * (2 * DI) + d;
  f32x4 zero = {0.f, 0.f, 0.f, 0.f};
  f32x4 xm = (l > 0)        ? *(const f32x4*)(base - 2 * DI) : zero;
  f32x4 xc = *(const f32x4*)(base);
  f32x4 xp = (l < LSEQ - 1) ? *(const f32x4*)(base + 2 * DI) : zero;

  bf16x4 o;
  #pragma unroll
  for (int j = 0; j < 4; ++j) {
    float w0 = conv_w[(d + j) * 3 + 0];
    float w1 = conv_w[(d + j) * 3 + 1];
    float w2 = conv_w[(d + j) * 3 + 2];
    float v = fmaf(w0, xm[j], fmaf(w1, xc[j], fmaf(w2, xp[j], conv_b[d + j])));
    v = v * sigmoidf_(v);
    o[j] = (bf16)v;
  }
  *(bf16x4*)(xconv + (size_t)bl * DI + d) = o;
}

// ---------------- dt precompute: per (b,t,d) pack {dt, dt*u} as f16x2 ----------
// Written into the dead x_in half of xz: dtp[bl*4096 + d] (u32 slots).
__global__ __launch_bounds__(256) void dtprep_kernel(
    const float* __restrict__ proj, const bf16* __restrict__ xconv,
    const float* __restrict__ W_dt, const float* __restrict__ b_dt,
    unsigned int* __restrict__ dtp) {
  int i = blockIdx.x * 256 + threadIdx.x;  // over BL*DI/4 = 2,097,152
  int d4 = (i & 511) * 4;
  int bl = i >> 9;
  float dtraw = proj[(size_t)bl * 128];
  f32x4 wd = *(const f32x4*)(W_dt + d4);
  f32x4 bd = *(const f32x4*)(b_dt + d4);
  bf16x4 uu = *(const bf16x4*)(xconv + (size_t)bl * DI + d4);
  uint4 o;
  #pragma unroll
  for (int j = 0; j < 4; ++j) {
    float s  = fmaf(dtraw, wd[j], bd[j]);
    float dt = (s > 15.f) ? s : __logf(1.f + __expf(s));  // softplus
    float dtu = dt * (float)uu[j];
    f16x2 pk = pack_f16x2(dt, dtu);
    ((unsigned int*)&o)[j] = __builtin_bit_cast(unsigned int, pk);
  }
  *(uint4*)(dtp + (size_t)bl * 4096 + d4) = o;
}

// ---------------- chunked SSM scan ----------------
// wave = 2 channels x 32 states; lane = half*32 + n.

__global__ __launch_bounds__(256) void scan_phase1(
    const float* __restrict__ proj, const unsigned int* __restrict__ dtp,
    const float* __restrict__ A_log, const float* __restrict__ alpha,
    float* __restrict__ Pbuf, float* __restrict__ Hbuf) {
  int wid = threadIdx.x >> 6, lane = threadIdx.x & 63;
  int half = lane >> 5, n = lane & 31;
  int pair = blockIdx.x * 4 + wid;   // 0..2047
  int c = blockIdx.y;                // 0..NC-1
  int b = pair >> 10;
  int d = ((pair & 1023) << 1) | half;

  float A_real = -__expf(A_log[d * DST + n]);
  float aG  = sigmoidf_(alpha[0]), omA = 1.f - aG;

  const float* pb = proj + ((size_t)b * LSEQ + c * LC) * 128;
  const unsigned int* dc = dtp + ((size_t)b * LSEQ + c * LC) * 4096 + d;

  float h = 0.f, P = 1.f;
  #pragma unroll 4
  for (int t = 0; t < LC; ++t) {
    f16x2 dw = __builtin_bit_cast(f16x2, dc[(size_t)t * 4096]);
    float dt = (float)dw[0], dtu = (float)dw[1];
    float Bv = pb[(size_t)t * 128 + 1 + n];
    float dtA = dt * A_real;
    float ex  = __expf(dtA);
    float den = fmaf(-0.5f, dtA, 1.000001f);
    float rec = __builtin_amdgcn_rcpf(den);
    float Ad  = fmaf(aG, ex, omA * rec);
    P *= Ad;
    h = fmaf(Ad, h, dtu * Bv);
  }
  size_t idx = ((size_t)c * 2048 + pair) * 64 + lane;
  Pbuf[idx] = P;
  Hbuf[idx] = h;
}

__global__ __launch_bounds__(256) void scan_phase2(
    const float* __restrict__ Pbuf, float* __restrict__ Hbuf) {
  int wid = threadIdx.x >> 6, lane = threadIdx.x & 63;
  int pair = blockIdx.x * 4 + wid;
  float P[NC], hl[NC];
  #pragma unroll
  for (int c = 0; c < NC; ++c) {
    size_t idx = ((size_t)c * 2048 + pair) * 64 + lane;
    P[c]  = Pbuf[idx];
    hl[c] = Hbuf[idx];
  }
  float H = 0.f;
  #pragma unroll
  for (int c = 0; c < NC; ++c) {
    size_t idx = ((size_t)c * 2048 + pair) * 64 + lane;
    Hbuf[idx] = H;              // start state for chunk c
    H = fmaf(P[c], H, hl[c]);   // end state of chunk c
  }
}

// phase3: recompute from true start state, reduce y (2 steps packed f16x2),
// fused D_skip + gate( silu(z) ) and bf16 store.
__global__ __launch_bounds__(256) void scan_phase3(
    const float* __restrict__ proj, const unsigned int* __restrict__ dtp,
    const float* __restrict__ xzf,   // same buffer as dtp; z at col 2048+d
    const bf16* __restrict__ xconv,
    const float* __restrict__ A_log, const float* __restrict__ D_skip,
    const float* __restrict__ alpha, const float* __restrict__ Hbuf,
    bf16* __restrict__ yb) {
  int wid = threadIdx.x >> 6, lane = threadIdx.x & 63;
  int half = lane >> 5, n = lane & 31;
  int pair = blockIdx.x * 4 + wid;
  int c = blockIdx.y;
  int b = pair >> 10;
  int d = ((pair & 1023) << 1) | half;

  float A_real = -__expf(A_log[d * DST + n]);
  float aG  = sigmoidf_(alpha[0]), omA = 1.f - aG;
  float Dsk = D_skip[d];

  const float* pb = proj  + ((size_t)b * LSEQ + c * LC) * 128;
  const unsigned int* dc = dtp + ((size_t)b * LSEQ + c * LC) * 4096 + d;
  const float* zc = xzf  + ((size_t)b * LSEQ + c * LC) * 4096 + 2048 + d;
  const bf16*  uc = xconv + ((size_t)b * LSEQ + c * LC) * DI + d;
  bf16*        yc = yb    + ((size_t)b * LSEQ + c * LC) * DI + d;

  float h = Hbuf[((size_t)c * 2048 + pair) * 64 + lane];

  #pragma unroll 2
  for (int t = 0; t < LC; t += 2) {
    // step t
    f16x2 dw0 = __builtin_bit_cast(f16x2, dc[(size_t)t * 4096]);
    float Bv0 = pb[(size_t)t * 128 + 1 + n];
    float Cv0 = pb[(size_t)t * 128 + 33 + n];
    float dtA0 = (float)dw0[0] * A_real;
    float Ad0  = fmaf(aG, __expf(dtA0),
                      omA * __builtin_amdgcn_rcpf(fmaf(-0.5f, dtA0, 1.000001f)));
    h = fmaf(Ad0, h, (float)dw0[1] * Bv0);
    float part0 = Cv0 * h;
    // step t+1
    f16x2 dw1 = __builtin_bit_cast(f16x2, dc[(size_t)(t + 1) * 4096]);
    float Bv1 = pb[(size_t)(t + 1) * 128 + 1 + n];
    float Cv1 = pb[(size_t)(t + 1) * 128 + 33 + n];
    float dtA1 = (float)dw1[0] * A_real;
    float Ad1  = fmaf(aG, __expf(dtA1),
                      omA * __builtin_amdgcn_rcpf(fmaf(-0.5f, dtA1, 1.000001f)));
    h = fmaf(Ad1, h, (float)dw1[1] * Bv1);
    float part1 = Cv1 * h;

    // packed 2-step reduce over n (stays within each 32-lane half)
    f16x2 pk = pack_f16x2(part0, part1);
    #pragma unroll
    for (int m = 1; m <= 16; m <<= 1) {
      int q = __shfl_xor(__builtin_bit_cast(int, pk), m);
      pk = pk + __builtin_bit_cast(f16x2, q);
    }
    if (n == 0) {
      float u0 = (float)uc[(size_t)t * DI];
      float u1 = (float)uc[(size_t)(t + 1) * DI];
      float z0 = zc[(size_t)t * 4096];
      float z1 = zc[(size_t)(t + 1) * 4096];
      float y0 = fmaf(Dsk, u0, (float)pk[0]);
      float y1 = fmaf(Dsk, u1, (float)pk[1]);
      y0 *= z0 * sigmoidf_(z0);
      y1 *= z1 * sigmoidf_(z1);
      yc[(size_t)t * DI]       = (bf16)y0;
      yc[(size_t)(t + 1) * DI] = (bf16)y1;
    }
  }
}

// ---------------- launch ----------------
extern "C" void kernel_launch(void* const* d_in, const int* in_sizes, int n_in,
                              void* d_out, int out_size, void* d_ws, size_t ws_size,
                              hipStream_t stream) {
  const float* x      = (const float*)d_in[0];
  const float* W_in   = (const float*)d_in[1];
  const float* conv_w = (const float*)d_in[2];
  const float* conv_b = (const float*)d_in[3];
  const float* A_log  = (const float*)d_in[4];
  const float* D_skip = (const float*)d_in[5];
  const float* W_xprj = (const float*)d_in[6];
  const float* W_dt   = (const float*)d_in[7];
  const float* b_dt   = (const float*)d_in[8];
  const float* alpha  = (const float*)d_in[9];
  const float* W_out  = (const float*)d_in[10];

  char* ws = (char*)d_ws;
  float* xz    = (float*)(ws + 0);            // (4096,4096) f32: 67,108,864 B
  bf16*  xconv = (bf16*) (ws + 67108864);     // (4096,2048) bf16: 16,777,216 B
  float* proj  = (float*)(ws + 83886080);     // (4096,128)  f32:  2,097,152 B
  bf16*  yb    = (bf16*) (ws + 102760448);    // (4096,2048) bf16: 16,777,216 B
  bf16*  xb    = (bf16*) (ws + 119537664);    // (4096,1024) bf16:  8,388,608 B
  bf16*  winb  = (bf16*) (ws + 127926272);    // (4096,1024) bf16:  8,388,608 B
  bf16*  woutb = (bf16*) (ws + 136314880);    // (1024,2048) bf16:  4,194,304 B
  bf16*  wxpb  = (bf16*) (ws + 140509184);    // (128,2048)  bf16:    524,288 B
  // P/H scan buffers reuse xb/winb (both dead after GEMM1):
  float* Pbuf = (float*)xb;    // 16*2048*64*4 = 8,388,608 B
  float* Hbuf = (float*)winb;  // 8,388,608 B
  // dtp reuses the x_in half of xz (cols 0..2047), dead after conv_silu.
  unsigned int* dtp = (unsigned int*)xz;

  float* out = (float*)d_out;  // (4096, 1024) f32

  // casts
  cast_bf16_kernel<<<4096, 256, 0, stream>>>(x, xb, BL * DM / 4);
  cast_bf16_kernel<<<4096, 256, 0, stream>>>(W_in, winb, 2 * DI * DM / 4);
  cast_bf16_kernel<<<2048, 256, 0, stream>>>(W_out, woutb, DM * DI / 4);
  padcast_wxp_kernel<<<256, 256, 0, stream>>>(W_xprj, wxpb);

  // xz = x @ W_in.T   (M=4096, N=4096, K=1024)
  gemm_bt<<<dim3(32, 32), 256, 0, stream>>>(xb, winb, xz, BL, 2 * DI, DM);

  // x_conv = silu(conv1d(x_in))
  conv_silu_kernel<<<8192, 256, 0, stream>>>(xz, xconv, conv_w, conv_b);

  // proj = x_conv @ W_xproj.T  (N padded to 128)
  gemm_bt<<<dim3(1, 32), 256, 0, stream>>>(xconv, wxpb, proj, BL, 128, DI);

  // dt/dtu precompute (overwrites x_in half of xz)
  dtprep_kernel<<<8192, 256, 0, stream>>>(proj, xconv, W_dt, b_dt, dtp);

  // chunked scan
  scan_phase1<<<dim3(512, NC), 256, 0, stream>>>(proj, dtp, A_log, alpha,
                                                 Pbuf, Hbuf);
  scan_phase2<<<512, 256, 0, stream>>>(Pbuf, Hbuf);
  scan_phase3<<<dim3(512, NC), 256, 0, stream>>>(proj, dtp, xz, xconv, A_log,
                                                 D_skip, alpha, Hbuf, yb);

  // out = y @ W_out.T  (M=4096, N=1024, K=2048)
  gemm_bt<<<dim3(8, 32), 256, 0, stream>>>(yb, woutb, out, BL, DM, DI);
}

// Round 5
// 394.934 us; speedup vs baseline: 3.0461x; 1.6715x over previous
//
#include <hip/hip_runtime.h>

// Mamba3 SSM layer: B=2, L=2048, D_MODEL=1024, D_INNER=2048, D_STATE=32
#define DM   1024
#define DI   2048
#define DST  32
#define NB   2
#define LSEQ 2048
#define BL   (NB*LSEQ)   // 4096 rows
#define LC   64          // scan chunk length
#define NC   32          // number of chunks (LC*NC == LSEQ)

using bf16   = __bf16;
using bf16x4 = __attribute__((ext_vector_type(4))) __bf16;
using bf16x8 = __attribute__((ext_vector_type(8))) __bf16;
using f32x4  = __attribute__((ext_vector_type(4))) float;
using f16x2  = __attribute__((ext_vector_type(2))) _Float16;

static __device__ __forceinline__ float sigmoidf_(float x) {
  return 1.f / (1.f + __expf(-x));
}

static __device__ __forceinline__ f16x2 pack_f16x2(float a, float b) {
  return __builtin_bit_cast(f16x2, __builtin_amdgcn_cvt_pkrtz(a, b));
}

static __device__ __forceinline__ float exp2_(float x) {
#if __has_builtin(__builtin_amdgcn_exp2f)
  return __builtin_amdgcn_exp2f(x);
#else
  return exp2f(x);
#endif
}

// ---------------- cast kernels ----------------
__global__ __launch_bounds__(256) void cast_bf16_kernel(
    const float* __restrict__ in, bf16* __restrict__ out, int n4) {
  int i = blockIdx.x * 256 + threadIdx.x;
  if (i >= n4) return;
  f32x4 v = ((const f32x4*)in)[i];
  bf16x4 o;
  #pragma unroll
  for (int j = 0; j < 4; ++j) o[j] = (bf16)v[j];
  ((bf16x4*)out)[i] = o;
}

// W_xproj (65,2048) -> bf16 padded+PERMUTED to (128,2048):
// out rows 0..31 = B rows (src 1..32), 32..63 = C rows (src 33..64),
// row 127 = dt_raw (src 0), rest zero.  => proj row: [B|C|pad|dtraw]
__global__ __launch_bounds__(256) void padcast_wxp_kernel(
    const float* __restrict__ in, bf16* __restrict__ out) {
  int i = blockIdx.x * 256 + threadIdx.x;   // over 128*2048/4 = 65536
  int k4 = i & 511;
  int r  = i >> 9;
  int src = (r < 64) ? (r + 1) : ((r == 127) ? 0 : -1);
  f32x4 v = {0.f, 0.f, 0.f, 0.f};
  if (src >= 0) v = *(const f32x4*)(in + (size_t)src * 2048 + k4 * 4);
  bf16x4 o;
  #pragma unroll
  for (int j = 0; j < 4; ++j) o[j] = (bf16)v[j];
  ((bf16x4*)out)[i] = o;
}

// ---------------- bf16 MFMA GEMM: C[M][N] = A[M][K] * B[N][K]^T ----------------
__global__ __launch_bounds__(256) void gemm_bt(
    const bf16* __restrict__ A, const bf16* __restrict__ B,
    float* __restrict__ C, int M, int N, int K) {
  __shared__ bf16 As[128][40];
  __shared__ bf16 Bs[128][40];

  int tid  = threadIdx.x;
  int bm   = blockIdx.y, bn = blockIdx.x;
  int row0 = bm * 128, col0 = bn * 128;
  int w    = tid >> 6, lane = tid & 63;
  int wr   = w >> 1, wc = w & 1;
  int lr   = lane & 15, lk = lane >> 4;

  f32x4 acc[4][4];
  #pragma unroll
  for (int i = 0; i < 4; ++i)
    #pragma unroll
    for (int j = 0; j < 4; ++j) acc[i][j] = f32x4{0.f, 0.f, 0.f, 0.f};

  int srow = tid >> 1;
  int scol = (tid & 1) * 16;
  const bf16* Ag = A + (size_t)(row0 + srow) * K + scol;
  const bf16* Bg = B + (size_t)(col0 + srow) * K + scol;

  for (int k0 = 0; k0 < K; k0 += 32) {
    *(bf16x8*)&As[srow][scol]     = *(const bf16x8*)(Ag + k0);
    *(bf16x8*)&As[srow][scol + 8] = *(const bf16x8*)(Ag + k0 + 8);
    *(bf16x8*)&Bs[srow][scol]     = *(const bf16x8*)(Bg + k0);
    *(bf16x8*)&Bs[srow][scol + 8] = *(const bf16x8*)(Bg + k0 + 8);
    __syncthreads();

    bf16x8 af[4], bff[4];
    #pragma unroll
    for (int mi = 0; mi < 4; ++mi)
      af[mi] = *(const bf16x8*)&As[wr * 64 + mi * 16 + lr][lk * 8];
    #pragma unroll
    for (int ni = 0; ni < 4; ++ni)
      bff[ni] = *(const bf16x8*)&Bs[wc * 64 + ni * 16 + lr][lk * 8];

    #pragma unroll
    for (int mi = 0; mi < 4; ++mi)
      #pragma unroll
      for (int ni = 0; ni < 4; ++ni)
        acc[mi][ni] = __builtin_amdgcn_mfma_f32_16x16x32_bf16(
            af[mi], bff[ni], acc[mi][ni], 0, 0, 0);
    __syncthreads();
  }

  #pragma unroll
  for (int mi = 0; mi < 4; ++mi)
    #pragma unroll
    for (int ni = 0; ni < 4; ++ni) {
      int r0 = row0 + wr * 64 + mi * 16 + lk * 4;
      int c  = col0 + wc * 64 + ni * 16 + lr;
      #pragma unroll
      for (int r = 0; r < 4; ++r)
        C[(size_t)(r0 + r) * N + c] = acc[mi][ni][r];
    }
}

// ---------------- depthwise conv3 + SiLU -> bf16 ----------------
__global__ __launch_bounds__(256) void conv_silu_kernel(
    const float* __restrict__ xz, bf16* __restrict__ xconv,
    const float* __restrict__ conv_w, const float* __restrict__ conv_b) {
  int i = blockIdx.x * 256 + threadIdx.x;  // over BL * DI/4
  int d4 = i & 511;
  int d  = d4 * 4;
  int bl = i >> 9;
  int l  = bl & (LSEQ - 1);

  const float* base = xz + (size_t)bl * (2 * DI) + d;
  f32x4 zero = {0.f, 0.f, 0.f, 0.f};
  f32x4 xm = (l > 0)        ? *(const f32x4*)(base - 2 * DI) : zero;
  f32x4 xc = *(const f32x4*)(base);
  f32x4 xp = (l < LSEQ - 1) ? *(const f32x4*)(base + 2 * DI) : zero;

  bf16x4 o;
  #pragma unroll
  for (int j = 0; j < 4; ++j) {
    float w0 = conv_w[(d + j) * 3 + 0];
    float w1 = conv_w[(d + j) * 3 + 1];
    float w2 = conv_w[(d + j) * 3 + 2];
    float v = fmaf(w0, xm[j], fmaf(w1, xc[j], fmaf(w2, xp[j], conv_b[d + j])));
    v = v * sigmoidf_(v);
    o[j] = (bf16)v;
  }
  *(bf16x4*)(xconv + (size_t)bl * DI + d) = o;
}

// ---------------- dt precompute: per (b,t,d) pack {dt, dt*u} as f16x2 ----------
// Written into the dead x_in half of xz: dtp[bl*4096 + d] (u32 slots).
__global__ __launch_bounds__(256) void dtprep_kernel(
    const float* __restrict__ proj, const bf16* __restrict__ xconv,
    const float* __restrict__ W_dt, const float* __restrict__ b_dt,
    unsigned int* __restrict__ dtp) {
  int i = blockIdx.x * 256 + threadIdx.x;  // over BL*DI/4 = 2,097,152
  int d4 = (i & 511) * 4;
  int bl = i >> 9;
  float dtraw = proj[(size_t)bl * 128 + 127];   // dt_raw now at col 127
  f32x4 wd = *(const f32x4*)(W_dt + d4);
  f32x4 bd = *(const f32x4*)(b_dt + d4);
  bf16x4 uu = *(const bf16x4*)(xconv + (size_t)bl * DI + d4);
  uint4 o;
  #pragma unroll
  for (int j = 0; j < 4; ++j) {
    float s  = fmaf(dtraw, wd[j], bd[j]);
    float dt = (s > 15.f) ? s : __logf(1.f + __expf(s));  // softplus
    float dtu = dt * (float)uu[j];
    f16x2 pk = pack_f16x2(dt, dtu);
    ((unsigned int*)&o)[j] = __builtin_bit_cast(unsigned int, pk);
  }
  *(uint4*)(dtp + (size_t)bl * 4096 + d4) = o;
}

// ---------------- chunked SSM scan, d-major: lane = d, 32 states in-register --
// Grid: (DI/256, NB, NC), block 256 = 4 waves x 64 d-lanes.

__global__ __launch_bounds__(256, 2) void scan_phase1(
    const float* __restrict__ proj, const unsigned int* __restrict__ dtp,
    const float* __restrict__ A_log, const float* __restrict__ alpha,
    float* __restrict__ Pbuf, float* __restrict__ Hbuf) {
  int wid = threadIdx.x >> 6, lane = threadIdx.x & 63;
  int d = blockIdx.x * 256 + wid * 64 + lane;
  int b = blockIdx.y, c = blockIdx.z;

  float aG = sigmoidf_(alpha[0]), omA = 1.f - aG;

  float Ar2[DST];   // -exp(A_log)*log2(e)
  #pragma unroll
  for (int n = 0; n < DST; n += 4) {
    f32x4 al = *(const f32x4*)(A_log + (size_t)d * DST + n);
    #pragma unroll
    for (int j = 0; j < 4; ++j) Ar2[n + j] = -__expf(al[j]) * 1.44269504f;
  }

  const float* pb = proj + ((size_t)b * LSEQ + c * LC) * 128;
  const unsigned int* dc = dtp + ((size_t)b * LSEQ + c * LC) * 4096 + d;

  float h[DST], P[DST];
  #pragma unroll
  for (int n = 0; n < DST; ++n) { h[n] = 0.f; P[n] = 1.f; }

  #pragma unroll 2
  for (int t = 0; t < LC; ++t) {
    f16x2 dw = __builtin_bit_cast(f16x2, dc[(size_t)t * 4096]);
    float dt = (float)dw[0], dtu = (float)dw[1];
    const float* pr = pb + (size_t)t * 128;
    #pragma unroll
    for (int n4 = 0; n4 < 8; ++n4) {
      f32x4 Bq = *(const f32x4*)(pr + n4 * 4);   // wave-uniform
      #pragma unroll
      for (int j = 0; j < 4; ++j) {
        int n = n4 * 4 + j;
        float t1  = dt * Ar2[n];                       // = dtA*log2e
        float ex  = exp2_(t1);
        float den = fmaf(t1, -0.34657359f, 1.000001f); // 1 - 0.5*dtA + 1e-6
        float Ad  = fmaf(aG, ex, omA * __builtin_amdgcn_rcpf(den));
        P[n] *= Ad;
        h[n] = fmaf(Ad, h[n], dtu * Bq[j]);
      }
    }
  }
  size_t ob = (((size_t)c * NB + b) * DI + d) * DST;
  #pragma unroll
  for (int n = 0; n < DST; n += 4) {
    f32x4 pv = {P[n], P[n + 1], P[n + 2], P[n + 3]};
    f32x4 hv = {h[n], h[n + 1], h[n + 2], h[n + 3]};
    *(f32x4*)(Pbuf + ob + n) = pv;
    *(f32x4*)(Hbuf + ob + n) = hv;
  }
}

// thread per (b,d,n): serial combine over NC chunks; coalesced per c-slab.
__global__ __launch_bounds__(256) void scan_phase2(
    const float* __restrict__ Pbuf, float* __restrict__ Hbuf) {
  int i = blockIdx.x * 256 + threadIdx.x;   // 0 .. NB*DI*DST-1 = 131071
  float H = 0.f;
  #pragma unroll
  for (int c = 0; c < NC; ++c) {
    size_t idx = (size_t)c * (NB * DI * DST) + i;
    float P  = Pbuf[idx];
    float hl = Hbuf[idx];
    Hbuf[idx] = H;              // start state for chunk c
    H = fmaf(P, H, hl);         // end state of chunk c
  }
}

// phase3: re-run chunk from true start state; in-lane n-reduce; fused gate.
__global__ __launch_bounds__(256, 2) void scan_phase3(
    const float* __restrict__ proj, const unsigned int* __restrict__ dtp,
    const float* __restrict__ xzf,   // z at row col 2048+d
    const bf16* __restrict__ xconv,
    const float* __restrict__ A_log, const float* __restrict__ D_skip,
    const float* __restrict__ alpha, const float* __restrict__ Hbuf,
    bf16* __restrict__ yb) {
  int wid = threadIdx.x >> 6, lane = threadIdx.x & 63;
  int d = blockIdx.x * 256 + wid * 64 + lane;
  int b = blockIdx.y, c = blockIdx.z;

  float aG = sigmoidf_(alpha[0]), omA = 1.f - aG;
  float Dsk = D_skip[d];

  float Ar2[DST];
  #pragma unroll
  for (int n = 0; n < DST; n += 4) {
    f32x4 al = *(const f32x4*)(A_log + (size_t)d * DST + n);
    #pragma unroll
    for (int j = 0; j < 4; ++j) Ar2[n + j] = -__expf(al[j]) * 1.44269504f;
  }

  float h[DST];
  size_t ob = (((size_t)c * NB + b) * DI + d) * DST;
  #pragma unroll
  for (int n = 0; n < DST; n += 4) {
    f32x4 hv = *(const f32x4*)(Hbuf + ob + n);
    #pragma unroll
    for (int j = 0; j < 4; ++j) h[n + j] = hv[j];
  }

  const float* pb = proj + ((size_t)b * LSEQ + c * LC) * 128;
  const unsigned int* dc = dtp + ((size_t)b * LSEQ + c * LC) * 4096 + d;
  const bf16*  uc = xconv + ((size_t)b * LSEQ + c * LC) * DI + d;
  const float* zc = xzf + ((size_t)b * LSEQ + c * LC) * 4096 + 2048 + d;
  bf16*        yc = yb  + ((size_t)b * LSEQ + c * LC) * DI + d;

  #pragma unroll 2
  for (int t = 0; t < LC; ++t) {
    f16x2 dw = __builtin_bit_cast(f16x2, dc[(size_t)t * 4096]);
    float dt = (float)dw[0], dtu = (float)dw[1];
    const float* pr = pb + (size_t)t * 128;
    float p0 = 0.f, p1 = 0.f, p2 = 0.f, p3 = 0.f;
    #pragma unroll
    for (int n4 = 0; n4 < 8; ++n4) {
      f32x4 Bq = *(const f32x4*)(pr + n4 * 4);        // wave-uniform
      f32x4 Cq = *(const f32x4*)(pr + 32 + n4 * 4);   // wave-uniform
      #pragma unroll
      for (int j = 0; j < 4; ++j) {
        int n = n4 * 4 + j;
        float t1  = dt * Ar2[n];
        float ex  = exp2_(t1);
        float den = fmaf(t1, -0.34657359f, 1.000001f);
        float Ad  = fmaf(aG, ex, omA * __builtin_amdgcn_rcpf(den));
        h[n] = fmaf(Ad, h[n], dtu * Bq[j]);
        if (j == 0)      p0 = fmaf(Cq[j], h[n], p0);
        else if (j == 1) p1 = fmaf(Cq[j], h[n], p1);
        else if (j == 2) p2 = fmaf(Cq[j], h[n], p2);
        else             p3 = fmaf(Cq[j], h[n], p3);
      }
    }
    float part = (p0 + p1) + (p2 + p3);
    float u = (float)uc[(size_t)t * DI];
    float z = zc[(size_t)t * 4096];
    float y = fmaf(Dsk, u, part);
    y *= z * sigmoidf_(z);
    yc[(size_t)t * DI] = (bf16)y;
  }
}

// ---------------- launch ----------------
extern "C" void kernel_launch(void* const* d_in, const int* in_sizes, int n_in,
                              void* d_out, int out_size, void* d_ws, size_t ws_size,
                              hipStream_t stream) {
  const float* x      = (const float*)d_in[0];
  const float* W_in   = (const float*)d_in[1];
  const float* conv_w = (const float*)d_in[2];
  const float* conv_b = (const float*)d_in[3];
  const float* A_log  = (const float*)d_in[4];
  const float* D_skip = (const float*)d_in[5];
  const float* W_xprj = (const float*)d_in[6];
  const float* W_dt   = (const float*)d_in[7];
  const float* b_dt   = (const float*)d_in[8];
  const float* alpha  = (const float*)d_in[9];
  const float* W_out  = (const float*)d_in[10];

  char* ws = (char*)d_ws;
  float* xz    = (float*)(ws + 0);            // (4096,4096) f32: 67,108,864 B
  bf16*  xconv = (bf16*) (ws + 67108864);     // (4096,2048) bf16: 16,777,216 B
  float* proj  = (float*)(ws + 83886080);     // (4096,128)  f32:  2,097,152 B
  float* Pbuf  = (float*)(ws + 85983232);     // NC*NB*DI*DST f32: 16,777,216 B
  bf16*  yb    = (bf16*) (ws + 102760448);    // (4096,2048) bf16: 16,777,216 B
  bf16*  xb    = (bf16*) (ws + 119537664);    // (4096,1024) bf16:  8,388,608 B (dead after GEMM1)
  bf16*  winb  = (bf16*) (ws + 127926272);    // (4096,1024) bf16:  8,388,608 B (dead after GEMM1)
  float* Hbuf  = (float*)(ws + 119537664);    // reuses xb+winb: 16,777,216 B
  bf16*  woutb = (bf16*) (ws + 136314880);    // (1024,2048) bf16:  4,194,304 B
  bf16*  wxpb  = (bf16*) (ws + 140509184);    // (128,2048)  bf16:    524,288 B
  // dtp reuses the x_in half of xz (cols 0..2047), dead after conv_silu.
  unsigned int* dtp = (unsigned int*)xz;

  float* out = (float*)d_out;  // (4096, 1024) f32

  // casts
  cast_bf16_kernel<<<4096, 256, 0, stream>>>(x, xb, BL * DM / 4);
  cast_bf16_kernel<<<4096, 256, 0, stream>>>(W_in, winb, 2 * DI * DM / 4);
  cast_bf16_kernel<<<2048, 256, 0, stream>>>(W_out, woutb, DM * DI / 4);
  padcast_wxp_kernel<<<256, 256, 0, stream>>>(W_xprj, wxpb);

  // xz = x @ W_in.T   (M=4096, N=4096, K=1024)
  gemm_bt<<<dim3(32, 32), 256, 0, stream>>>(xb, winb, xz, BL, 2 * DI, DM);

  // x_conv = silu(conv1d(x_in))
  conv_silu_kernel<<<8192, 256, 0, stream>>>(xz, xconv, conv_w, conv_b);

  // proj = x_conv @ W_xproj.T  (N padded to 128; rows permuted [B|C|pad|dtraw])
  gemm_bt<<<dim3(1, 32), 256, 0, stream>>>(xconv, wxpb, proj, BL, 128, DI);

  // dt/dtu precompute (overwrites x_in half of xz)
  dtprep_kernel<<<8192, 256, 0, stream>>>(proj, xconv, W_dt, b_dt, dtp);

  // chunked scan (d-major)
  scan_phase1<<<dim3(DI / 256, NB, NC), 256, 0, stream>>>(proj, dtp, A_log,
                                                          alpha, Pbuf, Hbuf);
  scan_phase2<<<512, 256, 0, stream>>>(Pbuf, Hbuf);
  scan_phase3<<<dim3(DI / 256, NB, NC), 256, 0, stream>>>(proj, dtp, xz, xconv,
                                                          A_log, D_skip, alpha,
                                                          Hbuf, yb);

  // out = y @ W_out.T  (M=4096, N=1024, K=2048)
  gemm_bt<<<dim3(8, 32), 256, 0, stream>>>(yb, woutb, out, BL, DM, DI);
}